// Round 6
// baseline (4324.918 us; speedup 1.0000x reference)
//
#include <hip/hip_runtime.h>
#include <math.h>

typedef _Float16 f16;
typedef _Float16 f16x8 __attribute__((ext_vector_type(8)));
typedef _Float16 f16x4 __attribute__((ext_vector_type(4)));
typedef float f32x4 __attribute__((ext_vector_type(4)));

#define B_D 64
#define B_H 512
#define TPB 512
#define PPB 128   // points per block (8 waves x 16 pts)
#define NC 16     // components per thread

// tanh(x) = 1 - 2/(e^{2x}+1); clamp avoids inf/inf
__device__ __forceinline__ float fast_tanh(float x) {
    x = fminf(fmaxf(x, -15.0f), 15.0f);
    float e = __expf(2.0f * x);
    return 1.0f - 2.0f / (e + 1.0f);
}

// reduce over the 4 lanes {c, c+16, c+32, c+48} holding one point
__device__ __forceinline__ float psum2(float v) {
    v += __shfl_xor(v, 16);
    v += __shfl_xor(v, 32);
    return v;
}

__device__ __forceinline__ float dot16(const float* a, const float* b) {
    float s0=0.f,s1=0.f,s2=0.f,s3=0.f;
#pragma unroll
    for (int d=0; d<NC; d+=4){ s0+=a[d]*b[d]; s1+=a[d+1]*b[d+1]; s2+=a[d+2]*b[d+2]; s3+=a[d+3]*b[d+3]; }
    return (s0+s1)+(s2+s3);
}

// o = mobius_add(sx*x, sy*y); per-lane 16 comps, dots reduced over the 4-lane point group
__device__ __forceinline__ void mobius16(const float* x, const float* y, float* o,
                                         float sx, float sy) {
    float xy=0.f, x2=0.f, y2=0.f;
#pragma unroll
    for (int d=0; d<NC; ++d){
        float a = sx*x[d], b = sy*y[d];
        xy += a*b; x2 += a*a; y2 += b*b;
    }
    xy = psum2(xy); x2 = psum2(x2); y2 = psum2(y2);
    float nx = 1.0f + 2.0f*xy + y2;
    float ny = 1.0f - x2;
    float inv = 1.0f / fmaxf(1.0f + 2.0f*xy + x2*y2, 1e-5f);
#pragma unroll
    for (int d=0; d<NC; ++d)
        o[d] = (nx*(sx*x[d]) + ny*(sy*y[d])) * inv;
}

// p += gradV-kick at q (grad factor -0.05*W2 folded into w2s).
// GEMM1 (swapped): act^T = W1^T . Q^T  via mfma 16x16x32, M=h(32 tiles), N=16 pts, K=64.
//   C-layout: lane(g,c): h = 16*mt + 4*g + r, pt = c.
// u = (1-t^2)*w2s  ->  u[mt] IS the B-frag of mfma 16x16x16 (k=4g+j within 16-block, n=c).
// GEMM2 (swapped): G^T = W1 . U^T  via mfma 16x16x16, M=d(4 tiles), K=512 (32 blocks).
//   C-layout: lane(g,c): d = 16*mt2 + 4*g + r, pt = c  == geometry register layout.
__device__ __forceinline__ void mlp_kick(const float* q, float* p,
        const f16* W1T, const f16* W1d, const float* b1s, const float* w2s,
        f16* qt, int g, int c) {
    int swz = (c & 7) << 4;
    // stage q tile [16 pt][64 d] f16, rows 128B, XOR-swizzled (wave-local, no barrier)
#pragma unroll
    for (int mt2=0; mt2<4; ++mt2){
        f16x4 v;
#pragma unroll
        for (int r=0;r<4;++r) v[r] = (f16)q[mt2*4+r];
        *(f16x4*)((char*)qt + ((c*128 + mt2*32 + g*8) ^ swz)) = v;
    }
    f32x4 acc[32];
#pragma unroll
    for (int mt=0; mt<32; ++mt)
        acc[mt] = *(const f32x4*)&b1s[mt*16 + 4*g];   // bias as C-init
    f16x8 bq[2];
#pragma unroll
    for (int kk=0; kk<2; ++kk)
        bq[kk] = *(const f16x8*)((const char*)qt + ((c*128 + kk*64 + g*16) ^ swz));
#pragma unroll
    for (int mt=0; mt<32; ++mt){
#pragma unroll
        for (int kk=0; kk<2; ++kk){
            f16x8 aw = *(const f16x8*)((const char*)W1T +
                        (((mt*16 + c)*128 + kk*64 + g*16) ^ swz));  // row h=16mt+c -> h&7==c&7
            acc[mt] = __builtin_amdgcn_mfma_f32_16x16x32_f16(aw, bq[kk], acc[mt], 0, 0, 0);
        }
    }
    f16x4 u[32];
#pragma unroll
    for (int mt=0; mt<32; ++mt){
        f32x4 w2v = *(const f32x4*)&w2s[mt*16 + 4*g];
#pragma unroll
        for (int r=0;r<4;++r){
            float t = fast_tanh(acc[mt][r]);
            u[mt][r] = (f16)((1.0f - t*t) * w2v[r]);
        }
    }
    f32x4 gacc[4];
#pragma unroll
    for (int mt2=0; mt2<4; ++mt2)
#pragma unroll
        for (int r=0;r<4;++r) gacc[mt2][r] = 0.0f;
#pragma unroll
    for (int kb=0; kb<32; ++kb){
#pragma unroll
        for (int mt2=0; mt2<4; ++mt2){
            f16x4 aw = *(const f16x4*)((const char*)W1d +
                        ((((mt2*16 + c)*512 + kb*16 + g*4)*2) ^ swz));  // row d=16mt2+c -> d&7==c&7
            gacc[mt2] = __builtin_amdgcn_mfma_f32_16x16x16f16(aw, u[kb], gacc[mt2], 0, 0, 0);
        }
    }
#pragma unroll
    for (int mt2=0; mt2<4; ++mt2)
#pragma unroll
        for (int r=0;r<4;++r) p[mt2*4+r] += gacc[mt2][r];
}

__global__ __launch_bounds__(TPB, 2)
void leapfrog_mfma(const float* __restrict__ gq, const float* __restrict__ gp,
                   const float* __restrict__ gW1, const float* __restrict__ gb1,
                   const float* __restrict__ gW2, float* __restrict__ out, int B) {
    __shared__ __align__(16) f16 W1T[B_H * B_D];    // [h][d] 64KB, serves GEMM1 A-frags
    __shared__ __align__(16) f16 W1d[B_D * B_H];    // [d][h] 64KB, serves GEMM2 A-frags
    __shared__ __align__(16) float b1s[B_H];
    __shared__ __align__(16) float w2s[B_H];        // -0.05*W2 pre-folded
    __shared__ __align__(16) f16 qtile[8][NC * B_D];// 2KB per wave

    int t = threadIdx.x;
    // stage W1 (f32 [64][512]) into both swizzled f16 copies
    for (int base = t*4; base < B_D*B_H; base += TPB*4) {
        float4 wv = *(const float4*)(gW1 + base);
        int d = base >> 9, h0 = base & 511;
        f16x4 hv; hv[0]=(f16)wv.x; hv[1]=(f16)wv.y; hv[2]=(f16)wv.z; hv[3]=(f16)wv.w;
        *(f16x4*)((char*)W1d + (((d*512 + h0)*2) ^ ((d&7)<<4))) = hv;
#pragma unroll
        for (int j=0;j<4;++j){
            int h = h0 + j;
            *(f16*)((char*)W1T + (((h*64 + d)*2) ^ ((h&7)<<4))) = hv[j];
        }
    }
    if (t < B_H) { b1s[t] = gb1[t]; w2s[t] = -0.05f * gW2[t]; }
    __syncthreads();

    int w = t >> 6, lane = t & 63, g = lane >> 4, c = lane & 15;
    f16* qt = qtile[w];
    int pt = blockIdx.x * PPB + w * NC + c;

    // geometry layout: lane owns point c of its wave-tile; comps d = 16*mt2 + 4*g + r
    float q[NC], p[NC], qn[NC];
#pragma unroll
    for (int mt2=0; mt2<4; ++mt2){
        float4 a = *(const float4*)(gq + (size_t)pt*B_D + mt2*16 + g*4);
        float4 b = *(const float4*)(gp + (size_t)pt*B_D + mt2*16 + g*4);
        q[4*mt2]=a.x; q[4*mt2+1]=a.y; q[4*mt2+2]=a.z; q[4*mt2+3]=a.w;
        p[4*mt2]=b.x; p[4*mt2+1]=b.y; p[4*mt2+2]=b.z; p[4*mt2+3]=b.w;
    }

#pragma unroll 1
    for (int step=0; step<4; ++step){
        // ---- first half-kick ----
        float qq = psum2(dot16(q,q));
        float pp = psum2(dot16(p,p));
        float s = fmaxf(1.0f - qq, 1e-5f);
        float c0 = 0.025f * pp * s;
#pragma unroll
        for (int d=0; d<NC; ++d) p[d] += c0*q[d];
        mlp_kick(q, p, W1T, W1d, b1s, w2s, qt, g, c);   // p = p_half

        // ---- drift: qn = exp_map(q, DT * p_half / lam^2) ----
        float fac = 0.025f * s * s;
        float ph2 = psum2(dot16(p,p));
        float vn = fmaxf(fac * sqrtf(ph2), 1e-15f);
        float th = fast_tanh(vn / s);
        float sc = th * fac / vn;
        {
            float qdp = psum2(dot16(q,p));
            float xy = sc*qdp;
            float y2 = sc*sc*ph2;
            float nx = 1.0f + 2.0f*xy + y2;
            float ny = 1.0f - qq;
            float inv = 1.0f / fmaxf(1.0f + 2.0f*xy + qq*y2, 1e-5f);
#pragma unroll
            for (int d=0; d<NC; ++d) qn[d] = (nx*q[d] + ny*sc*p[d]) * inv;
        }
        float qq2 = psum2(dot16(qn,qn));
        float s2 = fmaxf(1.0f - qq2, 1e-5f);

        // ---- parallel transport ----
        mobius16(q,  p, p, -1.0f, 1.0f);   // m1 = (-q) (+) p_half
        mobius16(qn, p, p,  1.0f, 1.0f);   // m2 = qn (+) m1
        mobius16(qn, q, q,  1.0f,-1.0f);   // m3 = qn (+) (-q)
        mobius16(q,  p, p, -1.0f, 1.0f);   // p = (-m3) (+) m2
        float ratio = s2 / s;
#pragma unroll
        for (int d=0; d<NC; ++d) p[d] *= ratio;

        // ---- second half-kick at qn ----
        float pp2 = psum2(dot16(p,p));
        float c2 = 0.025f * pp2 * s2;
#pragma unroll
        for (int d=0; d<NC; ++d) p[d] += c2*qn[d];
        mlp_kick(qn, p, W1T, W1d, b1s, w2s, qt, g, c);  // p = p_new

#pragma unroll
        for (int d=0; d<NC; ++d) q[d] = qn[d];
    }

    // output: concat(q, p) flat f32
    float* oq = out + (size_t)pt * B_D;
    float* op = out + (size_t)B * B_D + (size_t)pt * B_D;
#pragma unroll
    for (int mt2=0; mt2<4; ++mt2){
        *(float4*)(oq + mt2*16 + g*4) = make_float4(q[4*mt2],q[4*mt2+1],q[4*mt2+2],q[4*mt2+3]);
        *(float4*)(op + mt2*16 + g*4) = make_float4(p[4*mt2],p[4*mt2+1],p[4*mt2+2],p[4*mt2+3]);
    }
}

extern "C" void kernel_launch(void* const* d_in, const int* in_sizes, int n_in,
                              void* d_out, int out_size, void* d_ws, size_t ws_size,
                              hipStream_t stream) {
    const float* gq  = (const float*)d_in[0];
    const float* gp  = (const float*)d_in[1];
    const float* gW1 = (const float*)d_in[2];
    const float* gb1 = (const float*)d_in[3];
    const float* gW2 = (const float*)d_in[4];
    // d_in[5] = b2 : constant offset, no effect on gradients
    float* out = (float*)d_out;

    int B = in_sizes[0] / B_D;
    int blocks = (B + PPB - 1) / PPB;
    leapfrog_mfma<<<blocks, TPB, 0, stream>>>(gq, gp, gW1, gb1, gW2, out, B);
}

// Round 7
// 4044.282 us; speedup vs baseline: 1.0694x; 1.0694x over previous
//
#include <hip/hip_runtime.h>
#include <math.h>

typedef _Float16 f16;
typedef _Float16 f16x8 __attribute__((ext_vector_type(8)));
typedef _Float16 f16x4 __attribute__((ext_vector_type(4)));
typedef float f32x4 __attribute__((ext_vector_type(4)));

#define B_D 64
#define B_H 512
#define TPB 512
#define PPB 128   // points per block (8 waves x 16 pts)
#define NC 16     // components per thread

// tanh(x) = 1 - 2/(e^{2x}+1); clamp avoids inf/inf
__device__ __forceinline__ float fast_tanh(float x) {
    x = fminf(fmaxf(x, -15.0f), 15.0f);
    float e = __expf(2.0f * x);
    return 1.0f - 2.0f / (e + 1.0f);
}

// reduce over the 4 lanes {c, c+16, c+32, c+48} holding one point
__device__ __forceinline__ float psum2(float v) {
    v += __shfl_xor(v, 16);
    v += __shfl_xor(v, 32);
    return v;
}

__device__ __forceinline__ float dot16(const float* a, const float* b) {
    float s0=0.f,s1=0.f,s2=0.f,s3=0.f;
#pragma unroll
    for (int d=0; d<NC; d+=4){ s0+=a[d]*b[d]; s1+=a[d+1]*b[d+1]; s2+=a[d+2]*b[d+2]; s3+=a[d+3]*b[d+3]; }
    return (s0+s1)+(s2+s3);
}

// o = mobius_add(sx*x, sy*y); per-lane 16 comps, dots reduced over the 4-lane point group
__device__ __forceinline__ void mobius16(const float* x, const float* y, float* o,
                                         float sx, float sy) {
    float xy=0.f, x2=0.f, y2=0.f;
#pragma unroll
    for (int d=0; d<NC; ++d){
        float a = sx*x[d], b = sy*y[d];
        xy += a*b; x2 += a*a; y2 += b*b;
    }
    xy = psum2(xy); x2 = psum2(x2); y2 = psum2(y2);
    float nx = 1.0f + 2.0f*xy + y2;
    float ny = 1.0f - x2;
    float inv = 1.0f / fmaxf(1.0f + 2.0f*xy + x2*y2, 1e-5f);
#pragma unroll
    for (int d=0; d<NC; ++d)
        o[d] = (nx*(sx*x[d]) + ny*(sy*y[d])) * inv;
}

// p += gradV-kick at q (grad factor -0.05*W2 folded into w2s).
// Chunked GEMM1->tanh->GEMM2 pipeline: 4 h-tiles per chunk so the activation
// accumulator never exceeds 16 VGPRs (R6's acc[32] spilled ~6 GB to scratch).
// GEMM1 (swapped): act^T = W1^T.Q^T, mfma 16x16x32: lane(g,c) h=16mt+4g+r, pt=c.
// u = (1-t^2)*w2s is EXACTLY the B-frag of mfma 16x16x16 (k=4g+j, n=c).
// GEMM2 (swapped): G^T = W1.U^T, mfma 16x16x16: lane(g,c) d=16mt2+4g+r, pt=c
//   == geometry register layout, accumulate straight into p.
__device__ __forceinline__ void mlp_kick(const float* q, float* p,
        const f16* W1T, const f16* W1d, const float* b1s, const float* w2s,
        f16* qt, int g, int c) {
    int swz = (c & 7) << 4;
    // stage q tile [16 pt][64 d] f16, rows 128B, XOR-swizzled (wave-local, no barrier)
#pragma unroll
    for (int mt2=0; mt2<4; ++mt2){
        f16x4 v;
#pragma unroll
        for (int r=0;r<4;++r) v[r] = (f16)q[mt2*4+r];
        *(f16x4*)((char*)qt + ((c*128 + mt2*32 + g*8) ^ swz)) = v;
    }
    f16x8 bq[2];
#pragma unroll
    for (int kk=0; kk<2; ++kk)
        bq[kk] = *(const f16x8*)((const char*)qt + ((c*128 + kk*64 + g*16) ^ swz));

    f32x4 gacc[4];
#pragma unroll
    for (int mt2=0; mt2<4; ++mt2)
#pragma unroll
        for (int r=0;r<4;++r) gacc[mt2][r] = 0.0f;

#pragma unroll
    for (int ch=0; ch<8; ++ch){            // 4 h-tiles per chunk
        f32x4 acc[4];
#pragma unroll
        for (int i=0;i<4;++i)
            acc[i] = *(const f32x4*)&b1s[(ch*4+i)*16 + 4*g];   // bias as C-init
#pragma unroll
        for (int i=0;i<4;++i){
            int mt = ch*4 + i;
#pragma unroll
            for (int kk=0; kk<2; ++kk){
                f16x8 aw = *(const f16x8*)((const char*)W1T +
                            (((mt*16 + c)*128 + kk*64 + g*16) ^ swz));  // h=16mt+c -> h&7==c&7
                acc[i] = __builtin_amdgcn_mfma_f32_16x16x32_f16(aw, bq[kk], acc[i], 0, 0, 0);
            }
        }
        f16x4 u[4];
#pragma unroll
        for (int i=0;i<4;++i){
            f32x4 w2v = *(const f32x4*)&w2s[(ch*4+i)*16 + 4*g];
#pragma unroll
            for (int r=0;r<4;++r){
                float t = fast_tanh(acc[i][r]);
                u[i][r] = (f16)((1.0f - t*t) * w2v[r]);
            }
        }
#pragma unroll
        for (int i=0;i<4;++i){
            int kb = ch*4 + i;
#pragma unroll
            for (int mt2=0; mt2<4; ++mt2){
                f16x4 aw = *(const f16x4*)((const char*)W1d +
                            ((((mt2*16 + c)*512 + kb*16 + g*4)*2) ^ swz));  // d&7==c&7
                gacc[mt2] = __builtin_amdgcn_mfma_f32_16x16x16f16(aw, u[i], gacc[mt2], 0, 0, 0);
            }
        }
    }
#pragma unroll
    for (int mt2=0; mt2<4; ++mt2)
#pragma unroll
        for (int r=0;r<4;++r) p[mt2*4+r] += gacc[mt2][r];
}

__global__ __launch_bounds__(TPB, 2)
void leapfrog_mfma(const float* __restrict__ gq, const float* __restrict__ gp,
                   const float* __restrict__ gW1, const float* __restrict__ gb1,
                   const float* __restrict__ gW2, float* __restrict__ out, int B) {
    __shared__ __align__(16) f16 W1T[B_H * B_D];    // [h][d] 64KB, GEMM1 A-frags
    __shared__ __align__(16) f16 W1d[B_D * B_H];    // [d][h] 64KB, GEMM2 A-frags
    __shared__ __align__(16) float b1s[B_H];
    __shared__ __align__(16) float w2s[B_H];        // -0.05*W2 pre-folded
    __shared__ __align__(16) f16 qtile[8][NC * B_D];// 2KB per wave

    int t = threadIdx.x;
    // stage W1 (f32 [64][512]) into both swizzled f16 copies
    for (int base = t*4; base < B_D*B_H; base += TPB*4) {
        float4 wv = *(const float4*)(gW1 + base);
        int d = base >> 9, h0 = base & 511;
        f16x4 hv; hv[0]=(f16)wv.x; hv[1]=(f16)wv.y; hv[2]=(f16)wv.z; hv[3]=(f16)wv.w;
        *(f16x4*)((char*)W1d + (((d*512 + h0)*2) ^ ((d&7)<<4))) = hv;
#pragma unroll
        for (int j=0;j<4;++j){
            int h = h0 + j;
            *(f16*)((char*)W1T + (((h*64 + d)*2) ^ ((h&7)<<4))) = hv[j];
        }
    }
    if (t < B_H) { b1s[t] = gb1[t]; w2s[t] = -0.05f * gW2[t]; }
    __syncthreads();

    int w = t >> 6, lane = t & 63, g = lane >> 4, c = lane & 15;
    f16* qt = qtile[w];
    int pt = blockIdx.x * PPB + w * NC + c;

    // geometry layout: lane owns point c of its wave-tile; comps d = 16*mt2 + 4*g + r
    float q[NC], p[NC], qn[NC];
#pragma unroll
    for (int mt2=0; mt2<4; ++mt2){
        float4 a = *(const float4*)(gq + (size_t)pt*B_D + mt2*16 + g*4);
        float4 b = *(const float4*)(gp + (size_t)pt*B_D + mt2*16 + g*4);
        q[4*mt2]=a.x; q[4*mt2+1]=a.y; q[4*mt2+2]=a.z; q[4*mt2+3]=a.w;
        p[4*mt2]=b.x; p[4*mt2+1]=b.y; p[4*mt2+2]=b.z; p[4*mt2+3]=b.w;
    }

#pragma unroll 1
    for (int step=0; step<4; ++step){
        // ---- first half-kick ----
        float qq = psum2(dot16(q,q));
        float pp = psum2(dot16(p,p));
        float s = fmaxf(1.0f - qq, 1e-5f);
        float c0 = 0.025f * pp * s;
#pragma unroll
        for (int d=0; d<NC; ++d) p[d] += c0*q[d];
        mlp_kick(q, p, W1T, W1d, b1s, w2s, qt, g, c);   // p = p_half

        // ---- drift: qn = exp_map(q, DT * p_half / lam^2) ----
        float fac = 0.025f * s * s;
        float ph2 = psum2(dot16(p,p));
        float vn = fmaxf(fac * sqrtf(ph2), 1e-15f);
        float th = fast_tanh(vn / s);
        float sc = th * fac / vn;
        {
            float qdp = psum2(dot16(q,p));
            float xy = sc*qdp;
            float y2 = sc*sc*ph2;
            float nx = 1.0f + 2.0f*xy + y2;
            float ny = 1.0f - qq;
            float inv = 1.0f / fmaxf(1.0f + 2.0f*xy + qq*y2, 1e-5f);
#pragma unroll
            for (int d=0; d<NC; ++d) qn[d] = (nx*q[d] + ny*sc*p[d]) * inv;
        }
        float qq2 = psum2(dot16(qn,qn));
        float s2 = fmaxf(1.0f - qq2, 1e-5f);

        // ---- parallel transport ----
        mobius16(q,  p, p, -1.0f, 1.0f);   // m1 = (-q) (+) p_half
        mobius16(qn, p, p,  1.0f, 1.0f);   // m2 = qn (+) m1
        mobius16(qn, q, q,  1.0f,-1.0f);   // m3 = qn (+) (-q)
        mobius16(q,  p, p, -1.0f, 1.0f);   // p = (-m3) (+) m2
        float ratio = s2 / s;
#pragma unroll
        for (int d=0; d<NC; ++d) p[d] *= ratio;

        // ---- second half-kick at qn ----
        float pp2 = psum2(dot16(p,p));
        float c2 = 0.025f * pp2 * s2;
#pragma unroll
        for (int d=0; d<NC; ++d) p[d] += c2*qn[d];
        mlp_kick(qn, p, W1T, W1d, b1s, w2s, qt, g, c);  // p = p_new

#pragma unroll
        for (int d=0; d<NC; ++d) q[d] = qn[d];
    }

    // output: concat(q, p) flat f32
    float* oq = out + (size_t)pt * B_D;
    float* op = out + (size_t)B * B_D + (size_t)pt * B_D;
#pragma unroll
    for (int mt2=0; mt2<4; ++mt2){
        *(float4*)(oq + mt2*16 + g*4) = make_float4(q[4*mt2],q[4*mt2+1],q[4*mt2+2],q[4*mt2+3]);
        *(float4*)(op + mt2*16 + g*4) = make_float4(p[4*mt2],p[4*mt2+1],p[4*mt2+2],p[4*mt2+3]);
    }
}

extern "C" void kernel_launch(void* const* d_in, const int* in_sizes, int n_in,
                              void* d_out, int out_size, void* d_ws, size_t ws_size,
                              hipStream_t stream) {
    const float* gq  = (const float*)d_in[0];
    const float* gp  = (const float*)d_in[1];
    const float* gW1 = (const float*)d_in[2];
    const float* gb1 = (const float*)d_in[3];
    const float* gW2 = (const float*)d_in[4];
    // d_in[5] = b2 : constant offset, no effect on gradients
    float* out = (float*)d_out;

    int B = in_sizes[0] / B_D;
    int blocks = (B + PPB - 1) / PPB;
    leapfrog_mfma<<<blocks, TPB, 0, stream>>>(gq, gp, gW1, gb1, gW2, out, B);
}

// Round 9
// 4030.326 us; speedup vs baseline: 1.0731x; 1.0035x over previous
//
#include <hip/hip_runtime.h>
#include <math.h>

typedef _Float16 f16;
typedef _Float16 f16x8 __attribute__((ext_vector_type(8)));
typedef _Float16 f16x4 __attribute__((ext_vector_type(4)));
typedef float f32x4 __attribute__((ext_vector_type(4)));

#define B_D 64
#define B_H 512
#define TPB 512
#define PPB 128   // points per block (8 waves x 16 pts)
#define NC 16     // components per thread

// tanh(x) = 1 - 2/(e^{2x}+1); clamp avoids inf/inf
__device__ __forceinline__ float fast_tanh(float x) {
    x = fminf(fmaxf(x, -15.0f), 15.0f);
    float e = __expf(2.0f * x);
    return 1.0f - 2.0f / (e + 1.0f);
}

// reduce over the 4 lanes {c, c+16, c+32, c+48} holding one point
__device__ __forceinline__ float psum2(float v) {
    v += __shfl_xor(v, 16);
    v += __shfl_xor(v, 32);
    return v;
}

__device__ __forceinline__ float dot16(const float* a, const float* b) {
    float s0=0.f,s1=0.f,s2=0.f,s3=0.f;
#pragma unroll
    for (int d=0; d<NC; d+=4){ s0+=a[d]*b[d]; s1+=a[d+1]*b[d+1]; s2+=a[d+2]*b[d+2]; s3+=a[d+3]*b[d+3]; }
    return (s0+s1)+(s2+s3);
}

// o = mobius_add(sx*x, sy*y); per-lane 16 comps, dots reduced over the 4-lane point group
__device__ __forceinline__ void mobius16(const float* x, const float* y, float* o,
                                         float sx, float sy) {
    float xy=0.f, x2=0.f, y2=0.f;
#pragma unroll
    for (int d=0; d<NC; ++d){
        float a = sx*x[d], b = sy*y[d];
        xy += a*b; x2 += a*a; y2 += b*b;
    }
    xy = psum2(xy); x2 = psum2(x2); y2 = psum2(y2);
    float nx = 1.0f + 2.0f*xy + y2;
    float ny = 1.0f - x2;
    float inv = 1.0f / fmaxf(1.0f + 2.0f*xy + x2*y2, 1e-5f);
#pragma unroll
    for (int d=0; d<NC; ++d)
        o[d] = (nx*(sx*x[d]) + ny*(sy*y[d])) * inv;
}

// p += gradV-kick at q (grad factor -0.05*W2 folded into w2s).
// Chunked GEMM1->tanh->GEMM2 pipeline, 4 h-tiles per chunk.
// GEMM1 (swapped): act^T = W1^T.Q^T, mfma 16x16x32: lane(g,c) h=16mt+4g+r, pt=c.
// u = (1-t^2)*w2s is EXACTLY the B-frag of mfma 16x16x16 (k=4g+j, n=c).
// GEMM2 (swapped): G^T = W1.U^T, mfma 16x16x16: lane(g,c) d=16mt2+4g+r, pt=c
//   == geometry register layout, accumulate straight into p.
__device__ __forceinline__ void mlp_kick(const float* q, float* p,
        const f16* W1T, const f16* W1d, const float* b1s, const float* w2s,
        f16* qt, int g, int c) {
    int swz = (c & 7) << 4;
    // stage q tile [16 pt][64 d] f16, rows 128B, XOR-swizzled (wave-local, no barrier)
#pragma unroll
    for (int mt2=0; mt2<4; ++mt2){
        f16x4 v;
#pragma unroll
        for (int r=0;r<4;++r) v[r] = (f16)q[mt2*4+r];
        *(f16x4*)((char*)qt + ((c*128 + mt2*32 + g*8) ^ swz)) = v;
    }
    f16x8 bq[2];
#pragma unroll
    for (int kk=0; kk<2; ++kk)
        bq[kk] = *(const f16x8*)((const char*)qt + ((c*128 + kk*64 + g*16) ^ swz));

    f32x4 gacc[4];
#pragma unroll
    for (int mt2=0; mt2<4; ++mt2)
#pragma unroll
        for (int r=0;r<4;++r) gacc[mt2][r] = 0.0f;

#pragma unroll
    for (int ch=0; ch<8; ++ch){            // 4 h-tiles per chunk
        f32x4 acc[4];
#pragma unroll
        for (int i=0;i<4;++i)
            acc[i] = *(const f32x4*)&b1s[(ch*4+i)*16 + 4*g];   // bias as C-init
#pragma unroll
        for (int i=0;i<4;++i){
            int mt = ch*4 + i;
#pragma unroll
            for (int kk=0; kk<2; ++kk){
                f16x8 aw = *(const f16x8*)((const char*)W1T +
                            (((mt*16 + c)*128 + kk*64 + g*16) ^ swz));  // h=16mt+c -> h&7==c&7
                acc[i] = __builtin_amdgcn_mfma_f32_16x16x32_f16(aw, bq[kk], acc[i], 0, 0, 0);
            }
        }
        f16x4 u[4];
#pragma unroll
        for (int i=0;i<4;++i){
            f32x4 w2v = *(const f32x4*)&w2s[(ch*4+i)*16 + 4*g];
#pragma unroll
            for (int r=0;r<4;++r){
                float t = fast_tanh(acc[i][r]);
                u[i][r] = (f16)((1.0f - t*t) * w2v[r]);
            }
        }
#pragma unroll
        for (int i=0;i<4;++i){
            int kb = ch*4 + i;
#pragma unroll
            for (int mt2=0; mt2<4; ++mt2){
                f16x4 aw = *(const f16x4*)((const char*)W1d +
                            ((((mt2*16 + c)*512 + kb*16 + g*4)*2) ^ swz));  // d&7==c&7
                gacc[mt2] = __builtin_amdgcn_mfma_f32_16x16x16f16(aw, u[i], gacc[mt2], 0, 0, 0);
            }
        }
    }
#pragma unroll
    for (int mt2=0; mt2<4; ++mt2)
#pragma unroll
        for (int r=0;r<4;++r) p[mt2*4+r] += gacc[mt2][r];
}

__global__ __launch_bounds__(TPB, 1)
void leapfrog_mfma(const float* __restrict__ gq, const float* __restrict__ gp,
                   const float* __restrict__ gW1, const float* __restrict__ gb1,
                   const float* __restrict__ gW2, float* __restrict__ out, int B) {
    __shared__ __align__(16) f16 W1T[B_H * B_D];    // [h][d] 64KB, GEMM1 A-frags
    __shared__ __align__(16) f16 W1d[B_D * B_H];    // [d][h] 64KB, GEMM2 A-frags
    __shared__ __align__(16) float b1s[B_H];
    __shared__ __align__(16) float w2s[B_H];        // -0.05*W2 pre-folded
    __shared__ __align__(16) f16 qtile[8][NC * B_D];// 2KB per wave

    int t = threadIdx.x;
    // stage W1 (f32 [64][512]) into both swizzled f16 copies
    for (int base = t*4; base < B_D*B_H; base += TPB*4) {
        float4 wv = *(const float4*)(gW1 + base);
        int d = base >> 9, h0 = base & 511;
        f16x4 hv; hv[0]=(f16)wv.x; hv[1]=(f16)wv.y; hv[2]=(f16)wv.z; hv[3]=(f16)wv.w;
        *(f16x4*)((char*)W1d + (((d*512 + h0)*2) ^ ((d&7)<<4))) = hv;
#pragma unroll
        for (int j=0;j<4;++j){
            int h = h0 + j;
            *(f16*)((char*)W1T + (((h*64 + d)*2) ^ ((h&7)<<4))) = hv[j];
        }
    }
    if (t < B_H) { b1s[t] = gb1[t]; w2s[t] = -0.05f * gW2[t]; }
    __syncthreads();

    int w = t >> 6, lane = t & 63, g = lane >> 4, c = lane & 15;
    f16* qt = qtile[w];
    int pt = blockIdx.x * PPB + w * NC + c;

    // geometry layout: lane owns point c of its wave-tile; comps d = 16*mt2 + 4*g + r
    float q[NC], p[NC], qn[NC];
#pragma unroll
    for (int mt2=0; mt2<4; ++mt2){
        float4 a = *(const float4*)(gq + (size_t)pt*B_D + mt2*16 + g*4);
        float4 b = *(const float4*)(gp + (size_t)pt*B_D + mt2*16 + g*4);
        q[4*mt2]=a.x; q[4*mt2+1]=a.y; q[4*mt2+2]=a.z; q[4*mt2+3]=a.w;
        p[4*mt2]=b.x; p[4*mt2+1]=b.y; p[4*mt2+2]=b.z; p[4*mt2+3]=b.w;
    }

#pragma unroll 1
    for (int step=0; step<4; ++step){
        // ---- first half-kick ----
        float qq = psum2(dot16(q,q));
        float pp = psum2(dot16(p,p));
        float s = fmaxf(1.0f - qq, 1e-5f);
        float c0 = 0.025f * pp * s;
#pragma unroll
        for (int d=0; d<NC; ++d) p[d] += c0*q[d];
        mlp_kick(q, p, W1T, W1d, b1s, w2s, qt, g, c);   // p = p_half

        // ---- drift: qn = exp_map(q, DT * p_half / lam^2) ----
        float fac = 0.025f * s * s;
        float ph2 = psum2(dot16(p,p));
        float vn = fmaxf(fac * sqrtf(ph2), 1e-15f);
        float th = fast_tanh(vn / s);
        float sc = th * fac / vn;
        {
            float qdp = psum2(dot16(q,p));
            float xy = sc*qdp;
            float y2 = sc*sc*ph2;
            float nx = 1.0f + 2.0f*xy + y2;
            float ny = 1.0f - qq;
            float inv = 1.0f / fmaxf(1.0f + 2.0f*xy + qq*y2, 1e-5f);
#pragma unroll
            for (int d=0; d<NC; ++d) qn[d] = (nx*q[d] + ny*sc*p[d]) * inv;
        }
        float qq2 = psum2(dot16(qn,qn));
        float s2 = fmaxf(1.0f - qq2, 1e-5f);

        // ---- parallel transport ----
        mobius16(q,  p, p, -1.0f, 1.0f);   // m1 = (-q) (+) p_half
        mobius16(qn, p, p,  1.0f, 1.0f);   // m2 = qn (+) m1
        mobius16(qn, q, q,  1.0f,-1.0f);   // m3 = qn (+) (-q)
        mobius16(q,  p, p, -1.0f, 1.0f);   // p = (-m3) (+) m2
        float ratio = s2 / s;
#pragma unroll
        for (int d=0; d<NC; ++d) p[d] *= ratio;

        // ---- second half-kick at qn ----
        float pp2 = psum2(dot16(p,p));
        float c2 = 0.025f * pp2 * s2;
#pragma unroll
        for (int d=0; d<NC; ++d) p[d] += c2*qn[d];
        mlp_kick(qn, p, W1T, W1d, b1s, w2s, qt, g, c);  // p = p_new

#pragma unroll
        for (int d=0; d<NC; ++d) q[d] = qn[d];
    }

    // output: concat(q, p) flat f32
    float* oq = out + (size_t)pt * B_D;
    float* op = out + (size_t)B * B_D + (size_t)pt * B_D;
#pragma unroll
    for (int mt2=0; mt2<4; ++mt2){
        *(float4*)(oq + mt2*16 + g*4) = make_float4(q[4*mt2],q[4*mt2+1],q[4*mt2+2],q[4*mt2+3]);
        *(float4*)(op + mt2*16 + g*4) = make_float4(p[4*mt2],p[4*mt2+1],p[4*mt2+2],p[4*mt2+3]);
    }
}

extern "C" void kernel_launch(void* const* d_in, const int* in_sizes, int n_in,
                              void* d_out, int out_size, void* d_ws, size_t ws_size,
                              hipStream_t stream) {
    const float* gq  = (const float*)d_in[0];
    const float* gp  = (const float*)d_in[1];
    const float* gW1 = (const float*)d_in[2];
    const float* gb1 = (const float*)d_in[3];
    const float* gW2 = (const float*)d_in[4];
    // d_in[5] = b2 : constant offset, no effect on gradients
    float* out = (float*)d_out;

    int B = in_sizes[0] / B_D;
    int blocks = (B + PPB - 1) / PPB;
    leapfrog_mfma<<<blocks, TPB, 0, stream>>>(gq, gp, gW1, gb1, gW2, out, B);
}

// Round 10
// 602.634 us; speedup vs baseline: 7.1767x; 6.6878x over previous
//
#include <hip/hip_runtime.h>
#include <math.h>

typedef _Float16 f16;
typedef _Float16 f16x8 __attribute__((ext_vector_type(8)));
typedef _Float16 f16x4 __attribute__((ext_vector_type(4)));
typedef float f32x4 __attribute__((ext_vector_type(4)));

#define B_D 64
#define B_H 512
#define TPB 512
#define PPB 128   // points per block (8 waves x 16 pts)
#define NC 16     // components per thread

// tanh(x) = 1 - 2/(e^{2x}+1); clamp avoids inf/inf
__device__ __forceinline__ float fast_tanh(float x) {
    x = fminf(fmaxf(x, -15.0f), 15.0f);
    float e = __expf(2.0f * x);
    return 1.0f - 2.0f / (e + 1.0f);
}

// reduce over the 4 lanes {c, c+16, c+32, c+48} holding one point
__device__ __forceinline__ float psum2(float v) {
    v += __shfl_xor(v, 16);
    v += __shfl_xor(v, 32);
    return v;
}

__device__ __forceinline__ float dot16(const float* a, const float* b) {
    float s0=0.f,s1=0.f,s2=0.f,s3=0.f;
#pragma unroll
    for (int d=0; d<NC; d+=4){ s0+=a[d]*b[d]; s1+=a[d+1]*b[d+1]; s2+=a[d+2]*b[d+2]; s3+=a[d+3]*b[d+3]; }
    return (s0+s1)+(s2+s3);
}

// o = mobius_add(sx*x, sy*y); per-lane 16 comps, dots reduced over the 4-lane point group
__device__ __forceinline__ void mobius16(const float* x, const float* y, float* o,
                                         float sx, float sy) {
    float xy=0.f, x2=0.f, y2=0.f;
#pragma unroll
    for (int d=0; d<NC; ++d){
        float a = sx*x[d], b = sy*y[d];
        xy += a*b; x2 += a*a; y2 += b*b;
    }
    xy = psum2(xy); x2 = psum2(x2); y2 = psum2(y2);
    float nx = 1.0f + 2.0f*xy + y2;
    float ny = 1.0f - x2;
    float inv = 1.0f / fmaxf(1.0f + 2.0f*xy + x2*y2, 1e-5f);
#pragma unroll
    for (int d=0; d<NC; ++d)
        o[d] = (nx*(sx*x[d]) + ny*(sy*y[d])) * inv;
}

// p += gradV-kick at q. FULLY SCALARIZED: no ext-vector ARRAYS anywhere in
// this function (R6-R9 showed ~5.7GB/launch scratch traffic; suspected
// stack-allocated ext-vector aggregates re-read per MFMA). All fragments are
// named SSA values; h-loop is a real loop (unroll 1) with chunk=1.
// GEMM1 (swapped): act^T = W1^T.Q^T, mfma 16x16x32: lane(g,c) h=16mt+4g+r, pt=c.
// u = (1-t^2)*w2s is the B-frag of mfma 16x16x16 (k=4g+j, n=c).
// GEMM2 (swapped): G^T = W1.U^T, mfma 16x16x16: lane(g,c) d=16mt2+4g+r, pt=c
//   == geometry register layout, accumulate straight into p.
__device__ __forceinline__ void mlp_kick(const float* q, float* p,
        const f16* W1T, const f16* W1d, const float* b1s, const float* w2s,
        f16* qt, int g, int c) {
    const int swz = (c & 7) << 4;
    // stage q tile [16 pt][64 d] f16, rows 128B, XOR-swizzled (wave-local)
#pragma unroll
    for (int mt2=0; mt2<4; ++mt2){
        f16x4 v;
        v[0]=(f16)q[mt2*4+0]; v[1]=(f16)q[mt2*4+1];
        v[2]=(f16)q[mt2*4+2]; v[3]=(f16)q[mt2*4+3];
        *(f16x4*)((char*)qt + ((c*128 + mt2*32 + g*8) ^ swz)) = v;
    }
    const f16x8 bq0 = *(const f16x8*)((const char*)qt + ((c*128 +  0 + g*16) ^ swz));
    const f16x8 bq1 = *(const f16x8*)((const char*)qt + ((c*128 + 64 + g*16) ^ swz));

    f32x4 gacc0 = {0.f,0.f,0.f,0.f};
    f32x4 gacc1 = {0.f,0.f,0.f,0.f};
    f32x4 gacc2 = {0.f,0.f,0.f,0.f};
    f32x4 gacc3 = {0.f,0.f,0.f,0.f};

#pragma unroll 1
    for (int mt=0; mt<32; ++mt){
        // GEMM1 for one h-tile (16 h values), bias as C-init
        f32x4 acc = *(const f32x4*)&b1s[mt*16 + 4*g];
        const int base1 = (mt*16 + c)*128 + g*16;
        f16x8 aw0 = *(const f16x8*)((const char*)W1T + ((base1     ) ^ swz));
        f16x8 aw1 = *(const f16x8*)((const char*)W1T + ((base1 + 64) ^ swz));
        acc = __builtin_amdgcn_mfma_f32_16x16x32_f16(aw0, bq0, acc, 0, 0, 0);
        acc = __builtin_amdgcn_mfma_f32_16x16x32_f16(aw1, bq1, acc, 0, 0, 0);
        // tanh' * (-0.05*W2)  -> B-frag u for GEMM2
        const f32x4 w2v = *(const f32x4*)&w2s[mt*16 + 4*g];
        f16x4 u;
        {
            float t0 = fast_tanh(acc[0]); u[0] = (f16)((1.0f - t0*t0) * w2v[0]);
            float t1 = fast_tanh(acc[1]); u[1] = (f16)((1.0f - t1*t1) * w2v[1]);
            float t2 = fast_tanh(acc[2]); u[2] = (f16)((1.0f - t2*t2) * w2v[2]);
            float t3 = fast_tanh(acc[3]); u[3] = (f16)((1.0f - t3*t3) * w2v[3]);
        }
        // GEMM2: fold this h-tile into the 4 d-tiles
        const int kcol = (mt*16 + g*4)*2;
        f16x4 b0 = *(const f16x4*)((const char*)W1d + ((((0*16 + c)*512)*2 + kcol) ^ swz));
        gacc0 = __builtin_amdgcn_mfma_f32_16x16x16f16(b0, u, gacc0, 0, 0, 0);
        f16x4 b1 = *(const f16x4*)((const char*)W1d + ((((1*16 + c)*512)*2 + kcol) ^ swz));
        gacc1 = __builtin_amdgcn_mfma_f32_16x16x16f16(b1, u, gacc1, 0, 0, 0);
        f16x4 b2 = *(const f16x4*)((const char*)W1d + ((((2*16 + c)*512)*2 + kcol) ^ swz));
        gacc2 = __builtin_amdgcn_mfma_f32_16x16x16f16(b2, u, gacc2, 0, 0, 0);
        f16x4 b3 = *(const f16x4*)((const char*)W1d + ((((3*16 + c)*512)*2 + kcol) ^ swz));
        gacc3 = __builtin_amdgcn_mfma_f32_16x16x16f16(b3, u, gacc3, 0, 0, 0);
    }
    p[ 0] += gacc0[0]; p[ 1] += gacc0[1]; p[ 2] += gacc0[2]; p[ 3] += gacc0[3];
    p[ 4] += gacc1[0]; p[ 5] += gacc1[1]; p[ 6] += gacc1[2]; p[ 7] += gacc1[3];
    p[ 8] += gacc2[0]; p[ 9] += gacc2[1]; p[10] += gacc2[2]; p[11] += gacc2[3];
    p[12] += gacc3[0]; p[13] += gacc3[1]; p[14] += gacc3[2]; p[15] += gacc3[3];
}

__global__ __launch_bounds__(TPB, 1)
void leapfrog_mfma(const float* __restrict__ gq, const float* __restrict__ gp,
                   const float* __restrict__ gW1, const float* __restrict__ gb1,
                   const float* __restrict__ gW2, float* __restrict__ out, int B) {
    __shared__ __align__(16) f16 W1T[B_H * B_D];    // [h][d] 64KB, GEMM1 A-frags
    __shared__ __align__(16) f16 W1d[B_D * B_H];    // [d][h] 64KB, GEMM2 A-frags
    __shared__ __align__(16) float b1s[B_H];
    __shared__ __align__(16) float w2s[B_H];        // -0.05*W2 pre-folded
    __shared__ __align__(16) f16 qtile[8][NC * B_D];// 2KB per wave

    int t = threadIdx.x;
    // stage W1 (f32 [64][512]) into both swizzled f16 copies
    for (int base = t*4; base < B_D*B_H; base += TPB*4) {
        float4 wv = *(const float4*)(gW1 + base);
        int d = base >> 9, h0 = base & 511;
        f16x4 hv; hv[0]=(f16)wv.x; hv[1]=(f16)wv.y; hv[2]=(f16)wv.z; hv[3]=(f16)wv.w;
        *(f16x4*)((char*)W1d + (((d*512 + h0)*2) ^ ((d&7)<<4))) = hv;
#pragma unroll
        for (int j=0;j<4;++j){
            int h = h0 + j;
            *(f16*)((char*)W1T + (((h*64 + d)*2) ^ ((h&7)<<4))) = hv[j];
        }
    }
    if (t < B_H) { b1s[t] = gb1[t]; w2s[t] = -0.05f * gW2[t]; }
    __syncthreads();

    int w = t >> 6, lane = t & 63, g = lane >> 4, c = lane & 15;
    f16* qt = qtile[w];
    int pt = blockIdx.x * PPB + w * NC + c;

    // geometry layout: lane owns point c of its wave-tile; comps d = 16*mt2 + 4*g + r
    float q[NC], p[NC], qn[NC];
#pragma unroll
    for (int mt2=0; mt2<4; ++mt2){
        float4 a = *(const float4*)(gq + (size_t)pt*B_D + mt2*16 + g*4);
        float4 b = *(const float4*)(gp + (size_t)pt*B_D + mt2*16 + g*4);
        q[4*mt2]=a.x; q[4*mt2+1]=a.y; q[4*mt2+2]=a.z; q[4*mt2+3]=a.w;
        p[4*mt2]=b.x; p[4*mt2+1]=b.y; p[4*mt2+2]=b.z; p[4*mt2+3]=b.w;
    }

#pragma unroll 1
    for (int step=0; step<4; ++step){
        // ---- first half-kick ----
        float qq = psum2(dot16(q,q));
        float pp = psum2(dot16(p,p));
        float s = fmaxf(1.0f - qq, 1e-5f);
        float c0 = 0.025f * pp * s;
#pragma unroll
        for (int d=0; d<NC; ++d) p[d] += c0*q[d];
        mlp_kick(q, p, W1T, W1d, b1s, w2s, qt, g, c);   // p = p_half

        // ---- drift: qn = exp_map(q, DT * p_half / lam^2) ----
        float fac = 0.025f * s * s;
        float ph2 = psum2(dot16(p,p));
        float vn = fmaxf(fac * sqrtf(ph2), 1e-15f);
        float th = fast_tanh(vn / s);
        float sc = th * fac / vn;
        {
            float qdp = psum2(dot16(q,p));
            float xy = sc*qdp;
            float y2 = sc*sc*ph2;
            float nx = 1.0f + 2.0f*xy + y2;
            float ny = 1.0f - qq;
            float inv = 1.0f / fmaxf(1.0f + 2.0f*xy + qq*y2, 1e-5f);
#pragma unroll
            for (int d=0; d<NC; ++d) qn[d] = (nx*q[d] + ny*sc*p[d]) * inv;
        }
        float qq2 = psum2(dot16(qn,qn));
        float s2 = fmaxf(1.0f - qq2, 1e-5f);

        // ---- parallel transport ----
        mobius16(q,  p, p, -1.0f, 1.0f);   // m1 = (-q) (+) p_half
        mobius16(qn, p, p,  1.0f, 1.0f);   // m2 = qn (+) m1
        mobius16(qn, q, q,  1.0f,-1.0f);   // m3 = qn (+) (-q)
        mobius16(q,  p, p, -1.0f, 1.0f);   // p = (-m3) (+) m2
        float ratio = s2 / s;
#pragma unroll
        for (int d=0; d<NC; ++d) p[d] *= ratio;

        // ---- second half-kick at qn ----
        float pp2 = psum2(dot16(p,p));
        float c2 = 0.025f * pp2 * s2;
#pragma unroll
        for (int d=0; d<NC; ++d) p[d] += c2*qn[d];
        mlp_kick(qn, p, W1T, W1d, b1s, w2s, qt, g, c);  // p = p_new

#pragma unroll
        for (int d=0; d<NC; ++d) q[d] = qn[d];
    }

    // output: concat(q, p) flat f32
    float* oq = out + (size_t)pt * B_D;
    float* op = out + (size_t)B * B_D + (size_t)pt * B_D;
#pragma unroll
    for (int mt2=0; mt2<4; ++mt2){
        *(float4*)(oq + mt2*16 + g*4) = make_float4(q[4*mt2],q[4*mt2+1],q[4*mt2+2],q[4*mt2+3]);
        *(float4*)(op + mt2*16 + g*4) = make_float4(p[4*mt2],p[4*mt2+1],p[4*mt2+2],p[4*mt2+3]);
    }
}

extern "C" void kernel_launch(void* const* d_in, const int* in_sizes, int n_in,
                              void* d_out, int out_size, void* d_ws, size_t ws_size,
                              hipStream_t stream) {
    const float* gq  = (const float*)d_in[0];
    const float* gp  = (const float*)d_in[1];
    const float* gW1 = (const float*)d_in[2];
    const float* gb1 = (const float*)d_in[3];
    const float* gW2 = (const float*)d_in[4];
    // d_in[5] = b2 : constant offset, no effect on gradients
    float* out = (float*)d_out;

    int B = in_sizes[0] / B_D;
    int blocks = (B + PPB - 1) / PPB;
    leapfrog_mfma<<<blocks, TPB, 0, stream>>>(gq, gp, gW1, gb1, gW2, out, B);
}